// Round 10
// baseline (62.947 us; speedup 1.0000x reference)
//
#include <hip/hip_runtime.h>

static constexpr int kNodes = 100000;
static constexpr int kEdges = 1600000;
static constexpr int kPairs = kEdges / 2;
static constexpr int kD     = 128;

typedef float              fx4 __attribute__((ext_vector_type(4)));
typedef unsigned long long u64;

// ---------------------------------------------------------------------------
// R7 kernels, byte-identical. This round launches edge_attn 3x (idempotent)
// purely to measure its duration: K_edge = (dur - dur_R7 - gaps)/2.
// ---------------------------------------------------------------------------
__global__ __launch_bounds__(256) void node_pre(const float* __restrict__ emb,
                                                const float* __restrict__ W,
                                                float* __restrict__ uv) {
    const int l  = threadIdx.x & 15;   // lane within 16-group
    const int c0 = l * 8;

    fx4 w0a = *(const fx4*)&W[c0],       w0b = *(const fx4*)&W[c0 + 4];
    fx4 w1a = *(const fx4*)&W[256 + c0], w1b = *(const fx4*)&W[256 + c0 + 4];
    fx4 dua = w1a - w0a, dub = w1b - w0b;
    fx4 w2a = *(const fx4*)&W[128 + c0], w2b = *(const fx4*)&W[128 + c0 + 4];
    fx4 w3a = *(const fx4*)&W[384 + c0], w3b = *(const fx4*)&W[384 + c0 + 4];
    fx4 dva = w3a - w2a, dvb = w3b - w2b;

    const int n = (blockIdx.x * blockDim.x + threadIdx.x) >> 4;
    if (n >= kNodes) return;

    const fx4* row = (const fx4*)(emb + (size_t)n * kD + c0);
    fx4 ea = row[0];
    fx4 eb = row[1];

    float pu = ea.x*dua.x + ea.y*dua.y + ea.z*dua.z + ea.w*dua.w
             + eb.x*dub.x + eb.y*dub.y + eb.z*dub.z + eb.w*dub.w;
    float pv = ea.x*dva.x + ea.y*dva.y + ea.z*dva.z + ea.w*dva.w
             + eb.x*dvb.x + eb.y*dvb.y + eb.z*dvb.z + eb.w*dvb.w;

    float keep = (l & 1) ? pv : pu;
    float send = (l & 1) ? pu : pv;
    float x = keep + __shfl_xor(send, 1);
    x += __shfl_xor(x, 2);
    x += __shfl_xor(x, 4);
    x += __shfl_xor(x, 8);

    if (l < 2) uv[n * 2 + l] = x;   // 8B per node
}

__global__ __launch_bounds__(256) void edge_attn(const void* __restrict__ eiv,
                                                 const float* __restrict__ uv,
                                                 const float* __restrict__ b,
                                                 float* __restrict__ out) {
    const u64* ei64 = (const u64*)eiv;
    u64 hi = ei64[threadIdx.x & 63] >> 32;
    const bool is64 = (__ballot(hi != 0ull) == 0ull);

    const int e2 = blockIdx.x * blockDim.x + threadIdx.x;   // pair index
    if (e2 >= kPairs) return;

    int r0, r1, c0i, c1i;
    if (is64) {
        const u64* rr = ei64 + 2 * e2;
        const u64* cc = ei64 + kEdges + 2 * e2;
        r0  = (int)rr[0]; r1  = (int)rr[1];
        c0i = (int)cc[0]; c1i = (int)cc[1];
    } else {
        const int* ei32 = (const int*)eiv;
        r0  = ei32[2 * e2];          r1  = ei32[2 * e2 + 1];
        c0i = ei32[kEdges + 2 * e2]; c1i = ei32[kEdges + 2 * e2 + 1];
    }

    const float db = b[1] - b[0];

    float d0 = uv[2 * r0] + uv[2 * c0i + 1] + db;
    float d1 = uv[2 * r1] + uv[2 * c1i + 1] + db;

    float p00 = __builtin_amdgcn_rcpf(1.0f + __expf(d0));
    float p10 = __builtin_amdgcn_rcpf(1.0f + __expf(d1));

    fx4 o = {p00, 1.0f - p00, p10, 1.0f - p10};
    ((fx4*)out)[e2] = o;
}

extern "C" void kernel_launch(void* const* d_in, const int* in_sizes, int n_in,
                              void* d_out, int out_size, void* d_ws, size_t ws_size,
                              hipStream_t stream) {
    const float* emb = (const float*)d_in[0];
    const void*  ei  = d_in[1];
    const float* W   = (const float*)d_in[2];
    const float* b   = (const float*)d_in[3];
    float* out = (float*)d_out;

    float* uv = (float*)d_ws;   // 800 KB node table

    node_pre<<<(kNodes * 16 + 255) / 256, 256, 0, stream>>>(emb, W, uv);

    // edge_attn launched 3x: idempotent (pure function of ei, uv, b), so the
    // output is identical; the 2 extra launches measure K_edge via dur delta.
    edge_attn<<<(kPairs + 255) / 256, 256, 0, stream>>>(ei, uv, b, out);
    edge_attn<<<(kPairs + 255) / 256, 256, 0, stream>>>(ei, uv, b, out);
    edge_attn<<<(kPairs + 255) / 256, 256, 0, stream>>>(ei, uv, b, out);
}

// Round 11
// 33.836 us; speedup vs baseline: 1.8604x; 1.8604x over previous
//
#include <hip/hip_runtime.h>

static constexpr int kNodes = 100000;
static constexpr int kEdges = 1600000;
static constexpr int kQuads = kEdges / 4;   // 400000
static constexpr int kD     = 128;

typedef float              fx4 __attribute__((ext_vector_type(4)));
typedef unsigned long long u64;

// ---------------------------------------------------------------------------
// Phase 1: per-node difference dots (R7 math, split-array output).
//   u[n] = emb[n] · (W1-W0)[0:128]     v[n] = emb[n] · (W1-W0)[128:256]
// 16 lanes/node; transpose-reduce leaves u on even lanes, v on odd; lane 0
// stores u[n], lane 1 stores v[n]. Split arrays double the useful entries
// per 64B line for phase-2 gathers (16 vs 8).
// ---------------------------------------------------------------------------
__global__ __launch_bounds__(256) void node_pre(const float* __restrict__ emb,
                                                const float* __restrict__ W,
                                                float* __restrict__ u,
                                                float* __restrict__ v) {
    const int l  = threadIdx.x & 15;   // lane within 16-group
    const int c0 = l * 8;

    fx4 w0a = *(const fx4*)&W[c0],       w0b = *(const fx4*)&W[c0 + 4];
    fx4 w1a = *(const fx4*)&W[256 + c0], w1b = *(const fx4*)&W[256 + c0 + 4];
    fx4 dua = w1a - w0a, dub = w1b - w0b;
    fx4 w2a = *(const fx4*)&W[128 + c0], w2b = *(const fx4*)&W[128 + c0 + 4];
    fx4 w3a = *(const fx4*)&W[384 + c0], w3b = *(const fx4*)&W[384 + c0 + 4];
    fx4 dva = w3a - w2a, dvb = w3b - w2b;

    const int n = (blockIdx.x * blockDim.x + threadIdx.x) >> 4;
    if (n >= kNodes) return;

    const fx4* row = (const fx4*)(emb + (size_t)n * kD + c0);
    fx4 ea = row[0];
    fx4 eb = row[1];

    float pu = ea.x*dua.x + ea.y*dua.y + ea.z*dua.z + ea.w*dua.w
             + eb.x*dub.x + eb.y*dub.y + eb.z*dub.z + eb.w*dub.w;
    float pv = ea.x*dva.x + ea.y*dva.y + ea.z*dva.z + ea.w*dva.w
             + eb.x*dvb.x + eb.y*dvb.y + eb.z*dvb.z + eb.w*dvb.w;

    float keep = (l & 1) ? pv : pu;
    float send = (l & 1) ? pu : pv;
    float x = keep + __shfl_xor(send, 1);
    x += __shfl_xor(x, 2);
    x += __shfl_xor(x, 4);
    x += __shfl_xor(x, 8);

    if (l == 0) u[n] = x;
    if (l == 1) v[n] = x;
}

// L1-bypassing 4B gather: agent-scope relaxed atomic load -> global_load sc0,
// served from L2 without allocating/filling CU L1 (kills L1 fill-port
// serialization for random gathers; uv table is L2-resident).
__device__ inline float ld_l2(const float* p) {
    return __hip_atomic_load(p, __ATOMIC_RELAXED, __HIP_MEMORY_SCOPE_AGENT);
}

// ---------------------------------------------------------------------------
// Phase 2: 4 edges per thread. Batch: 8 coalesced index words -> 8 L1-bypass
// gathers issued back-to-back (MLP) -> 4 sigmoids -> 2 fx4 stores.
// d = u[r] + v[c] + (b1-b0);  p0 = 1/(1+e^d);  p1 = 1-p0.
// ---------------------------------------------------------------------------
__global__ __launch_bounds__(256) void edge_attn(const void* __restrict__ eiv,
                                                 const float* __restrict__ u,
                                                 const float* __restrict__ v,
                                                 const float* __restrict__ b,
                                                 float* __restrict__ out) {
    const u64* ei64 = (const u64*)eiv;
    u64 hiw = ei64[threadIdx.x & 63] >> 32;
    const bool is64 = (__ballot(hiw != 0ull) == 0ull);

    const int e4 = blockIdx.x * blockDim.x + threadIdx.x;   // quad index
    if (e4 >= kQuads) return;

    int r[4], c[4];
    if (is64) {
        const u64* rr = ei64 + 4 * (size_t)e4;
        const u64* cc = ei64 + kEdges + 4 * (size_t)e4;
#pragma unroll
        for (int k = 0; k < 4; ++k) {
            r[k] = (int)rr[k];
            c[k] = (int)cc[k];
        }
    } else {
        const int* ei32 = (const int*)eiv;
#pragma unroll
        for (int k = 0; k < 4; ++k) {
            r[k] = ei32[4 * e4 + k];
            c[k] = ei32[kEdges + 4 * e4 + k];
        }
    }

    // all 8 gathers issued before any use (one vmcnt wait covers them)
    float ug[4], vg[4];
#pragma unroll
    for (int k = 0; k < 4; ++k) ug[k] = ld_l2(&u[r[k]]);
#pragma unroll
    for (int k = 0; k < 4; ++k) vg[k] = ld_l2(&v[c[k]]);

    const float db = b[1] - b[0];
    float res[8];
#pragma unroll
    for (int k = 0; k < 4; ++k) {
        float d = ug[k] + vg[k] + db;
        float p = __builtin_amdgcn_rcpf(1.0f + __expf(d));
        res[2*k]   = p;
        res[2*k+1] = 1.0f - p;
    }

    fx4* o4 = (fx4*)out;
    fx4 oa = {res[0], res[1], res[2], res[3]};
    fx4 ob = {res[4], res[5], res[6], res[7]};
    o4[2 * e4]     = oa;
    o4[2 * e4 + 1] = ob;
}

extern "C" void kernel_launch(void* const* d_in, const int* in_sizes, int n_in,
                              void* d_out, int out_size, void* d_ws, size_t ws_size,
                              hipStream_t stream) {
    const float* emb = (const float*)d_in[0];
    const void*  ei  = d_in[1];
    const float* W   = (const float*)d_in[2];
    const float* b   = (const float*)d_in[3];
    float* out = (float*)d_out;

    float* u = (float*)d_ws;                         // 400 KB
    float* v = (float*)((char*)d_ws + 512 * 1024);   // 400 KB

    node_pre<<<(kNodes * 16 + 255) / 256, 256, 0, stream>>>(emb, W, u, v);
    edge_attn<<<(kQuads + 255) / 256, 256, 0, stream>>>(ei, u, v, b, out);
}